// Round 7
// baseline (596.530 us; speedup 1.0000x reference)
//
#include <hip/hip_runtime.h>
#include <stdint.h>

// K-means cluster aggregator, round 7: PROVEN 16x16x32 f16 MFMA lane semantics
// (rounds 2-4, 3x hardware-passed) + round-5 perf levers re-applied:
//   - A operand pre-fragmented in ws -> one contiguous 1KB coalesced load per (tile,step)
//   - software-pipelined double-buffered A/B register prefetch
//   - duplicate-center canonicalization (reference-exact routing for duplicate groups)
//   - counting-sort + balanced segmented reduction (proven round 4)
// Round-6 lesson: the 32x32x16 rewrite had a structural bug (canon null result proved
// it was not tie-breaking); reverted to the verified compute path.

typedef _Float16 f16x8  __attribute__((ext_vector_type(8)));
typedef float    f32x4  __attribute__((ext_vector_type(4)));

#define DD 512   // feature dim (fixed)
#define KK 1024  // clusters (fixed)

static __device__ __forceinline__ unsigned orderable(float s) {
    unsigned u = __float_as_uint(s);
    return (u & 0x80000000u) ? ~u : (u | 0x80000000u);
}

// ---- kernel 0a/0b: canonical representative per duplicate-center group ------------
__global__ void canon_first(const int* __restrict__ center_ind,
                            unsigned* __restrict__ firstk, int K) {
    int k = (int)(blockIdx.x * blockDim.x + threadIdx.x);
    if (k < K) atomicMin(&firstk[center_ind[k]], (unsigned)k);
}
__global__ void canon_map(const int* __restrict__ center_ind,
                          const unsigned* __restrict__ firstk,
                          unsigned* __restrict__ canon, int K) {
    int k = (int)(blockIdx.x * blockDim.x + threadIdx.x);
    if (k < K) canon[k] = firstk[center_ind[k]];
}

// ---- kernel 1: gather centers -> 16x16x32 A-fragment layout + fp32 ||c||^2 --------
// Fragment layout (f16 elems): center c -> tile t=c>>4, row r=c&15; 8-dim chunk j:
//   offset = ((t*64 + j)*16 + r) * 8          (per tile: 8192 f16 = 16 KB)
// Wave read at (tile t, 32-dim step s): lane l -> chunk j = 4s + (l>>4), row r = l&15
//   => within-step offset (l>>4)*128 + (l&15)*8 = l*8 -> contiguous 1 KB per (t,s).
__global__ void gather_centers(const float* __restrict__ nodes,
                               const int* __restrict__ center_ind,
                               _Float16* __restrict__ centf,    // [K*DD] fragmented
                               float* __restrict__ cent_sq,     // [K]
                               int K) {
    int k    = (int)blockIdx.x;
    int lane = (int)threadIdx.x;                 // 64 lanes; lane = chunk j
    int ci   = center_ind[k];
    const f32x4* p = reinterpret_cast<const f32x4*>(nodes + (size_t)ci * DD + lane * 8);
    f32x4 v0 = p[0], v1 = p[1];
    f16x8 h;
    h[0]=(_Float16)v0[0]; h[1]=(_Float16)v0[1]; h[2]=(_Float16)v0[2]; h[3]=(_Float16)v0[3];
    h[4]=(_Float16)v1[0]; h[5]=(_Float16)v1[1]; h[6]=(_Float16)v1[2]; h[7]=(_Float16)v1[3];
    int t = k >> 4, r = k & 15;
    *reinterpret_cast<f16x8*>(centf + ((size_t)((t * 64 + lane) * 16 + r) << 3)) = h;
    float ssq = v0[0]*v0[0]+v0[1]*v0[1]+v0[2]*v0[2]+v0[3]*v0[3]
              + v1[0]*v1[0]+v1[1]*v1[1]+v1[2]*v1[2]+v1[3]*v1[3];
    #pragma unroll
    for (int off = 32; off > 0; off >>= 1) ssq += __shfl_xor(ssq, off, 64);
    if (lane == 0) cent_sq[k] = ssq;
}

// ---- kernel 2: MFMA assign + histogram --------------------------------------------
// block: 64 nodes, 4 waves; wave w owns centers [w*256, (w+1)*256) as 4 outer iters
// of 64 centers (4 tiles of 16). Node LDS + B-read + epilogue are round-4 verbatim.
__launch_bounds__(256, 2)
__global__ void assign_mfma(const float* __restrict__ nodes,
                            const _Float16* __restrict__ centf,   // fragmented A
                            const float* __restrict__ cent_sq,    // [K]
                            const unsigned* __restrict__ canon,   // [K]
                            unsigned* __restrict__ assignment,    // [N]
                            unsigned* __restrict__ counts,        // [K], pre-zeroed
                            int N, int K) {
    __shared__ __align__(16) _Float16 nt[64 * DD];       // 64 KB, XOR-swizzled
    __shared__ float csq[KK];
    __shared__ unsigned long long best[64];

    const int tid = (int)threadIdx.x;
    const int n0  = (int)blockIdx.x * 64;

    // stage node tile -> f16 LDS (round-4 verbatim). f = it*256+tid: row = f>>6
    // (uniform per wave), dchunk = f&63 -> conflict-free swizzled writes.
    #pragma unroll
    for (int it = 0; it < 16; ++it) {
        int f   = it * 256 + tid;
        int row = f >> 6;
        int d0  = (f & 63) << 3;
        f32x4 v0 = {0.f,0.f,0.f,0.f}, v1 = {0.f,0.f,0.f,0.f};
        if (n0 + row < N) {
            const f32x4* p = reinterpret_cast<const f32x4*>(nodes + (size_t)(n0 + row) * DD + d0);
            v0 = p[0]; v1 = p[1];
        }
        f16x8 h;
        h[0]=(_Float16)v0[0]; h[1]=(_Float16)v0[1]; h[2]=(_Float16)v0[2]; h[3]=(_Float16)v0[3];
        h[4]=(_Float16)v1[0]; h[5]=(_Float16)v1[1]; h[6]=(_Float16)v1[2]; h[7]=(_Float16)v1[3];
        int byte = ((row << 10) + (d0 << 1)) ^ ((row & 7) << 4);
        *reinterpret_cast<f16x8*>(reinterpret_cast<char*>(nt) + byte) = h;
    }
    for (int j = tid; j < K;  j += 256) csq[j]  = cent_sq[j];
    for (int j = tid; j < 64; j += 256) best[j] = ~0ULL;
    __syncthreads();

    const int lane = tid & 63;
    const int wid  = tid >> 6;
    const int l15  = lane & 15;
    const int g    = lane >> 4;          // k-slice group (and C-row group)
    const int swz  = (l15 & 7) << 4;
    char* ntb = reinterpret_cast<char*>(nt);

    int bbase[4];
    #pragma unroll
    for (int nG = 0; nG < 4; ++nG) bbase[nG] = (((nG * 16 + l15) << 10) + (g << 4));

    // A-read: lane-linear 1KB per (tile,step):  aw + t_*8192 + s*512 + lane*8
    #define LA(Av, aw, s)                                                            \
        { _Pragma("unroll")                                                          \
          for (int t_ = 0; t_ < 4; ++t_)                                             \
              Av[t_] = *reinterpret_cast<const f16x8*>(                              \
                  (aw) + ((size_t)t_ << 13) + ((s) << 9) + (lane << 3)); }
    // B-read (round-4 verbatim): d0 = 32*s dims -> byte d0*2 = s<<6
    #define LB(Bv, s)                                                                \
        { _Pragma("unroll")                                                          \
          for (int nG = 0; nG < 4; ++nG)                                             \
              Bv[nG] = *reinterpret_cast<const f16x8*>(                              \
                  ntb + ((bbase[nG] + ((s) << 6)) ^ swz)); }
    #define MM(Av, Bv)                                                               \
        { _Pragma("unroll")                                                          \
          for (int t_ = 0; t_ < 4; ++t_)                                             \
              _Pragma("unroll")                                                      \
              for (int nG = 0; nG < 4; ++nG)                                         \
                  acc[t_][nG] = __builtin_amdgcn_mfma_f32_16x16x32_f16(              \
                      Av[t_], Bv[nG], acc[t_][nG], 0, 0, 0); }

    const int cw0 = wid * (K >> 2);
    #pragma unroll
    for (int t64 = 0; t64 < 4; ++t64) {
        const int cbase = cw0 + t64 * 64;                    // 4 tiles of 16 centers
        const _Float16* aw = centf + ((size_t)(cbase >> 4) << 13);

        f32x4 acc[4][4];                 // [center tile][node group]
        #pragma unroll
        for (int a = 0; a < 4; ++a)
            #pragma unroll
            for (int b = 0; b < 4; ++b) { f32x4 z = {0.f,0.f,0.f,0.f}; acc[a][b] = z; }

        f16x8 Aa[4], Ba[4], Ab[4], Bb[4];
        LA(Aa, aw, 0); LB(Ba, 0);
        #pragma unroll
        for (int s = 0; s < 16; s += 2) {
            LA(Ab, aw, s + 1); LB(Bb, s + 1);
            MM(Aa, Ba);
            if (s + 2 < 16) { LA(Aa, aw, s + 2); LB(Ba, s + 2); }
            MM(Ab, Bb);
        }

        // epilogue (round-4 verbatim): score = csq - 2*dot; packed min.
        // C/D map: col(node) = lane&15, row(center) = g*4 + q   [m89-verified]
        #pragma unroll
        for (int nG = 0; nG < 4; ++nG) {
            unsigned long long pk = ~0ULL;
            #pragma unroll
            for (int tC = 0; tC < 4; ++tC) {
                #pragma unroll
                for (int q = 0; q < 4; ++q) {
                    int c = cbase + tC * 16 + g * 4 + q;
                    float s = fmaf(-2.f, acc[tC][nG][q], csq[c]);
                    unsigned long long v =
                        ((unsigned long long)orderable(s) << 32) | (unsigned)c;
                    pk = v < pk ? v : pk;
                }
            }
            unsigned long long o;
            o = __shfl_xor(pk, 16, 64); pk = o < pk ? o : pk;
            o = __shfl_xor(pk, 32, 64); pk = o < pk ? o : pk;
            if (lane < 16) atomicMin(&best[nG * 16 + l15], pk);
        }
    }
    #undef LA
    #undef LB
    #undef MM

    __syncthreads();
    if (tid < 64 && n0 + tid < N) {
        unsigned k = (unsigned)(best[tid] & 0xffffffffu);
        k = canon[k];                    // duplicate groups -> smallest k (ref exact)
        assignment[n0 + tid] = k;
        atomicAdd(&counts[k], 1u);
    }
}

// ---- kernel 3: exclusive scan of counts -> cursor ---------------------------------
__global__ void scan_offsets(const unsigned* __restrict__ counts,
                             unsigned* __restrict__ cursor) {
    __shared__ unsigned s[KK];
    int t = (int)threadIdx.x;            // 1024
    unsigned c = counts[t];
    s[t] = c;
    __syncthreads();
    for (int off = 1; off < KK; off <<= 1) {
        unsigned v = (t >= off) ? s[t - off] : 0u;
        __syncthreads();
        s[t] += v;
        __syncthreads();
    }
    cursor[t] = s[t] - c;                // exclusive
}

// ---- kernel 4: scatter packed (k<<20 | node) keys into sorted slots ---------------
__global__ void scatter_idx(const unsigned* __restrict__ assignment,
                            unsigned* __restrict__ cursor,
                            unsigned* __restrict__ keys, int N) {
    int i = (int)(blockIdx.x * blockDim.x + threadIdx.x);
    if (i < N) {
        unsigned k = assignment[i];
        unsigned slot = atomicAdd(&cursor[k], 1u);
        keys[slot] = (k << 20) | (unsigned)i;   // N < 2^20, K < 2^10
    }
}

// ---- kernel 5: balanced segmented reduction over sorted slots ---------------------
#define CHUNK 32
__launch_bounds__(256, 4)
__global__ void aggregate3(const float* __restrict__ nodes,
                           const unsigned* __restrict__ keys,   // [N] packed
                           float* __restrict__ out, int N) {
    const int tid  = (int)threadIdx.x;
    const int wid  = tid >> 6;
    const int lane = tid & 63;
    const int base = ((int)blockIdx.x * 4 + wid) * CHUNK;
    if (base >= N) return;
    const int n    = min(CHUNK, N - base);

    int sI = base + (lane & 31);
    unsigned myk = (sI < N) ? keys[sI] : 0u;

    f32x4 a0 = {0.f,0.f,0.f,0.f}, a1 = {0.f,0.f,0.f,0.f};
    int curk = -1;
    auto flush = [&](void) {
        float* dst = out + ((size_t)curk << 9) + lane * 8;
        #pragma unroll
        for (int e = 0; e < 4; ++e) atomicAdd(dst + e, a0[e]);
        #pragma unroll
        for (int e = 0; e < 4; ++e) atomicAdd(dst + 4 + e, a1[e]);
    };

    int j = 0;
    while (j < n) {
        int b = n - j; if (b > 4) b = 4;
        f32x4 r[4][2];
        int   kk[4];
        #pragma unroll
        for (int t = 0; t < 4; ++t) {
            if (t < b) {
                unsigned key = __shfl(myk, j + t, 64);
                kk[t] = (int)(key >> 20);
                const f32x4* p = reinterpret_cast<const f32x4*>(
                    nodes + ((size_t)(key & 0xFFFFFu) << 9) + lane * 8);
                r[t][0] = p[0];
                r[t][1] = p[1];
            }
        }
        #pragma unroll
        for (int t = 0; t < 4; ++t) {
            if (t < b) {
                if (kk[t] != curk) {
                    if (curk >= 0) flush();
                    curk = kk[t];
                    f32x4 z = {0.f,0.f,0.f,0.f}; a0 = z; a1 = z;
                }
                a0 += r[t][0];
                a1 += r[t][1];
            }
        }
        j += 4;
    }
    if (curk >= 0) flush();
}

extern "C" void kernel_launch(void* const* d_in, const int* in_sizes, int n_in,
                              void* d_out, int out_size, void* d_ws, size_t ws_size,
                              hipStream_t stream) {
    const float* nodes      = (const float*)d_in[0];
    const int*   center_ind = (const int*)d_in[1];
    int K = in_sizes[1];                  // 1024
    int D = out_size / K;                 // 512 (DD)
    int N = in_sizes[0] / D;              // 100000

    char* ws = (char*)d_ws;
    _Float16* centf      = (_Float16*)ws;                          // K*DD*2 = 1 MB
    size_t    o          = (size_t)K * DD * 2;
    float*    cent_sq    = (float*)(ws + o);    o += (size_t)K * 4;
    unsigned* assignment = (unsigned*)(ws + o); o += (size_t)N * 4;
    unsigned* counts     = (unsigned*)(ws + o); o += (size_t)K * 4;
    unsigned* cursor     = (unsigned*)(ws + o); o += (size_t)K * 4;
    unsigned* firstk     = (unsigned*)(ws + o); o += (size_t)D * 4;
    unsigned* canon      = (unsigned*)(ws + o); o += (size_t)K * 4;
    unsigned* keys       = (unsigned*)(ws + o); o += (size_t)N * 4;
    float*    out        = (float*)d_out;

    hipMemsetAsync(counts, 0, (size_t)K * sizeof(unsigned), stream);
    hipMemsetAsync(firstk, 0xFF, (size_t)D * sizeof(unsigned), stream);
    hipMemsetAsync(out, 0, (size_t)out_size * sizeof(float), stream);

    canon_first<<<(K + 255) / 256, 256, 0, stream>>>(center_ind, firstk, K);
    canon_map<<<(K + 255) / 256, 256, 0, stream>>>(center_ind, firstk, canon, K);
    gather_centers<<<K, 64, 0, stream>>>(nodes, center_ind, centf, cent_sq, K);
    assign_mfma<<<(N + 63) / 64, 256, 0, stream>>>(nodes, centf, cent_sq, canon,
                                                   assignment, counts, N, K);
    scan_offsets<<<1, KK, 0, stream>>>(counts, cursor);
    scatter_idx<<<(N + 255) / 256, 256, 0, stream>>>(assignment, cursor, keys, N);
    aggregate3<<<(N + 4 * CHUNK - 1) / (4 * CHUNK), 256, 0, stream>>>(nodes, keys, out, N);
}

// Round 8
// 482.305 us; speedup vs baseline: 1.2368x; 1.2368x over previous
//
#include <hip/hip_runtime.h>
#include <stdint.h>

// K-means cluster aggregator, round 8: round-7 proven semantics + 4-deep counted-vmcnt
// software pipeline in the assign kernel (T3/T4 mechanism: prefetch distance 4 steps,
// loads in flight across steps, never drain to vmcnt(0) mid-loop).
//   - LA/LB/MM/epilogue lane semantics bit-identical to round 7 (hardware-passed).
//   - A register ring Ab[4][.], B ring Bb[2][.], prefetch wraps across t64 groups.
//   - everything outside assign_mfma unchanged from round 7.

typedef _Float16 f16x8  __attribute__((ext_vector_type(8)));
typedef float    f32x4  __attribute__((ext_vector_type(4)));

#define DD 512   // feature dim (fixed)
#define KK 1024  // clusters (fixed)

static __device__ __forceinline__ unsigned orderable(float s) {
    unsigned u = __float_as_uint(s);
    return (u & 0x80000000u) ? ~u : (u | 0x80000000u);
}

// ---- kernel 0a/0b: canonical representative per duplicate-center group ------------
__global__ void canon_first(const int* __restrict__ center_ind,
                            unsigned* __restrict__ firstk, int K) {
    int k = (int)(blockIdx.x * blockDim.x + threadIdx.x);
    if (k < K) atomicMin(&firstk[center_ind[k]], (unsigned)k);
}
__global__ void canon_map(const int* __restrict__ center_ind,
                          const unsigned* __restrict__ firstk,
                          unsigned* __restrict__ canon, int K) {
    int k = (int)(blockIdx.x * blockDim.x + threadIdx.x);
    if (k < K) canon[k] = firstk[center_ind[k]];
}

// ---- kernel 1: gather centers -> 16x16x32 A-fragment layout + fp32 ||c||^2 --------
// Fragment layout (f16 elems): center c -> tile t=c>>4, row r=c&15; 8-dim chunk j:
//   offset = ((t*64 + j)*16 + r) * 8          (per tile: 8192 f16 = 16 KB)
// Wave read at (tile t, 32-dim step s): lane l -> chunk j = 4s + (l>>4), row r = l&15
//   => within-step offset l*8 -> contiguous 1 KB per (t,s).
__global__ void gather_centers(const float* __restrict__ nodes,
                               const int* __restrict__ center_ind,
                               _Float16* __restrict__ centf,    // [K*DD] fragmented
                               float* __restrict__ cent_sq,     // [K]
                               int K) {
    int k    = (int)blockIdx.x;
    int lane = (int)threadIdx.x;                 // 64 lanes; lane = chunk j
    int ci   = center_ind[k];
    const f32x4* p = reinterpret_cast<const f32x4*>(nodes + (size_t)ci * DD + lane * 8);
    f32x4 v0 = p[0], v1 = p[1];
    f16x8 h;
    h[0]=(_Float16)v0[0]; h[1]=(_Float16)v0[1]; h[2]=(_Float16)v0[2]; h[3]=(_Float16)v0[3];
    h[4]=(_Float16)v1[0]; h[5]=(_Float16)v1[1]; h[6]=(_Float16)v1[2]; h[7]=(_Float16)v1[3];
    int t = k >> 4, r = k & 15;
    *reinterpret_cast<f16x8*>(centf + ((size_t)((t * 64 + lane) * 16 + r) << 3)) = h;
    float ssq = v0[0]*v0[0]+v0[1]*v0[1]+v0[2]*v0[2]+v0[3]*v0[3]
              + v1[0]*v1[0]+v1[1]*v1[1]+v1[2]*v1[2]+v1[3]*v1[3];
    #pragma unroll
    for (int off = 32; off > 0; off >>= 1) ssq += __shfl_xor(ssq, off, 64);
    if (lane == 0) cent_sq[k] = ssq;
}

// ---- kernel 2: MFMA assign + histogram --------------------------------------------
// block: 64 nodes, 4 waves; wave w owns centers [w*256, (w+1)*256) as 4 t64-groups
// of 64 centers (4 tiles of 16). 4-deep A ring, 2-deep B ring, cross-group prefetch.
__launch_bounds__(256, 2)
__global__ void assign_mfma(const float* __restrict__ nodes,
                            const _Float16* __restrict__ centf,   // fragmented A
                            const float* __restrict__ cent_sq,    // [K]
                            const unsigned* __restrict__ canon,   // [K]
                            unsigned* __restrict__ assignment,    // [N]
                            unsigned* __restrict__ counts,        // [K], pre-zeroed
                            int N, int K) {
    __shared__ __align__(16) _Float16 nt[64 * DD];       // 64 KB, XOR-swizzled
    __shared__ float csq[KK];
    __shared__ unsigned long long best[64];

    const int tid = (int)threadIdx.x;
    const int n0  = (int)blockIdx.x * 64;

    // stage node tile -> f16 LDS (round-4 verbatim).
    #pragma unroll
    for (int it = 0; it < 16; ++it) {
        int f   = it * 256 + tid;
        int row = f >> 6;
        int d0  = (f & 63) << 3;
        f32x4 v0 = {0.f,0.f,0.f,0.f}, v1 = {0.f,0.f,0.f,0.f};
        if (n0 + row < N) {
            const f32x4* p = reinterpret_cast<const f32x4*>(nodes + (size_t)(n0 + row) * DD + d0);
            v0 = p[0]; v1 = p[1];
        }
        f16x8 h;
        h[0]=(_Float16)v0[0]; h[1]=(_Float16)v0[1]; h[2]=(_Float16)v0[2]; h[3]=(_Float16)v0[3];
        h[4]=(_Float16)v1[0]; h[5]=(_Float16)v1[1]; h[6]=(_Float16)v1[2]; h[7]=(_Float16)v1[3];
        int byte = ((row << 10) + (d0 << 1)) ^ ((row & 7) << 4);
        *reinterpret_cast<f16x8*>(reinterpret_cast<char*>(nt) + byte) = h;
    }
    for (int j = tid; j < K;  j += 256) csq[j]  = cent_sq[j];
    for (int j = tid; j < 64; j += 256) best[j] = ~0ULL;
    __syncthreads();

    const int lane = tid & 63;
    const int wid  = tid >> 6;
    const int l15  = lane & 15;
    const int g    = lane >> 4;          // k-slice group (and C-row group)
    const int swz  = (l15 & 7) << 4;
    char* ntb = reinterpret_cast<char*>(nt);
    const int cw0 = wid * (K >> 2);      // 256 centers per wave

    int bbase[4];
    #pragma unroll
    for (int nG = 0; nG < 4; ++nG) bbase[nG] = (((nG * 16 + l15) << 10) + (g << 4));

    // A-read for global step gs (t64 = gs>>4, s = gs&15): 4 contiguous 1KB wave loads
    #define LA(dst, gs_)                                                             \
        { const int t64_ = (gs_) >> 4, s_ = (gs_) & 15;                              \
          const _Float16* aw_ = centf + ((size_t)((cw0 >> 4) + t64_ * 4) << 13);     \
          _Pragma("unroll")                                                          \
          for (int t_ = 0; t_ < 4; ++t_)                                             \
              dst[t_] = *reinterpret_cast<const f16x8*>(                             \
                  aw_ + ((size_t)t_ << 13) + (s_ << 9) + (lane << 3)); }
    // B-read (round-4 verbatim), periodic in s
    #define LB(dst, s_)                                                              \
        { _Pragma("unroll")                                                          \
          for (int nG = 0; nG < 4; ++nG)                                             \
              dst[nG] = *reinterpret_cast<const f16x8*>(                             \
                  ntb + ((bbase[nG] + ((s_) << 6)) ^ swz)); }
    #define MM(Av, Bv)                                                               \
        { _Pragma("unroll")                                                          \
          for (int t_ = 0; t_ < 4; ++t_)                                             \
              _Pragma("unroll")                                                      \
              for (int nG = 0; nG < 4; ++nG)                                         \
                  acc[t_][nG] = __builtin_amdgcn_mfma_f32_16x16x32_f16(              \
                      Av[t_], Bv[nG], acc[t_][nG], 0, 0, 0); }

    f16x8 Ab[4][4];      // 4-deep A ring  [depth][tile]
    f16x8 Bb[2][4];      // 2-deep B ring  [depth][nodeGroup]
    LA(Ab[0], 0); LA(Ab[1], 1); LA(Ab[2], 2); LA(Ab[3], 3);
    LB(Bb[0], 0); LB(Bb[1], 1);

    #pragma unroll
    for (int t64 = 0; t64 < 4; ++t64) {
        const int cbase = cw0 + t64 * 64;

        f32x4 acc[4][4];                 // [center tile][node group]
        #pragma unroll
        for (int a = 0; a < 4; ++a)
            #pragma unroll
            for (int b = 0; b < 4; ++b) { f32x4 z = {0.f,0.f,0.f,0.f}; acc[a][b] = z; }

        #pragma unroll
        for (int s = 0; s < 16; ++s) {
            const int gs = t64 * 16 + s;
            MM(Ab[gs & 3], Bb[gs & 1]);
            LB(Bb[gs & 1], (gs + 2) & 15);        // B periodic: same node tile
            if (gs + 4 < 64) LA(Ab[gs & 3], gs + 4);
        }

        // epilogue (round-4 verbatim): score = csq - 2*dot; packed min.
        // C/D map: col(node) = lane&15, row(center) = g*4 + q
        #pragma unroll
        for (int nG = 0; nG < 4; ++nG) {
            unsigned long long pk = ~0ULL;
            #pragma unroll
            for (int tC = 0; tC < 4; ++tC) {
                #pragma unroll
                for (int q = 0; q < 4; ++q) {
                    int c = cbase + tC * 16 + g * 4 + q;
                    float s = fmaf(-2.f, acc[tC][nG][q], csq[c]);
                    unsigned long long v =
                        ((unsigned long long)orderable(s) << 32) | (unsigned)c;
                    pk = v < pk ? v : pk;
                }
            }
            unsigned long long o;
            o = __shfl_xor(pk, 16, 64); pk = o < pk ? o : pk;
            o = __shfl_xor(pk, 32, 64); pk = o < pk ? o : pk;
            if (lane < 16) atomicMin(&best[nG * 16 + l15], pk);
        }
    }
    #undef LA
    #undef LB
    #undef MM

    __syncthreads();
    if (tid < 64 && n0 + tid < N) {
        unsigned k = (unsigned)(best[tid] & 0xffffffffu);
        k = canon[k];                    // duplicate groups -> smallest k (ref exact)
        assignment[n0 + tid] = k;
        atomicAdd(&counts[k], 1u);
    }
}

// ---- kernel 3: exclusive scan of counts -> cursor ---------------------------------
__global__ void scan_offsets(const unsigned* __restrict__ counts,
                             unsigned* __restrict__ cursor) {
    __shared__ unsigned s[KK];
    int t = (int)threadIdx.x;            // 1024
    unsigned c = counts[t];
    s[t] = c;
    __syncthreads();
    for (int off = 1; off < KK; off <<= 1) {
        unsigned v = (t >= off) ? s[t - off] : 0u;
        __syncthreads();
        s[t] += v;
        __syncthreads();
    }
    cursor[t] = s[t] - c;                // exclusive
}

// ---- kernel 4: scatter packed (k<<20 | node) keys into sorted slots ---------------
__global__ void scatter_idx(const unsigned* __restrict__ assignment,
                            unsigned* __restrict__ cursor,
                            unsigned* __restrict__ keys, int N) {
    int i = (int)(blockIdx.x * blockDim.x + threadIdx.x);
    if (i < N) {
        unsigned k = assignment[i];
        unsigned slot = atomicAdd(&cursor[k], 1u);
        keys[slot] = (k << 20) | (unsigned)i;   // N < 2^20, K < 2^10
    }
}

// ---- kernel 5: balanced segmented reduction over sorted slots ---------------------
#define CHUNK 32
__launch_bounds__(256, 4)
__global__ void aggregate3(const float* __restrict__ nodes,
                           const unsigned* __restrict__ keys,   // [N] packed
                           float* __restrict__ out, int N) {
    const int tid  = (int)threadIdx.x;
    const int wid  = tid >> 6;
    const int lane = tid & 63;
    const int base = ((int)blockIdx.x * 4 + wid) * CHUNK;
    if (base >= N) return;
    const int n    = min(CHUNK, N - base);

    int sI = base + (lane & 31);
    unsigned myk = (sI < N) ? keys[sI] : 0u;

    f32x4 a0 = {0.f,0.f,0.f,0.f}, a1 = {0.f,0.f,0.f,0.f};
    int curk = -1;
    auto flush = [&](void) {
        float* dst = out + ((size_t)curk << 9) + lane * 8;
        #pragma unroll
        for (int e = 0; e < 4; ++e) atomicAdd(dst + e, a0[e]);
        #pragma unroll
        for (int e = 0; e < 4; ++e) atomicAdd(dst + 4 + e, a1[e]);
    };

    int j = 0;
    while (j < n) {
        int b = n - j; if (b > 4) b = 4;
        f32x4 r[4][2];
        int   kk[4];
        #pragma unroll
        for (int t = 0; t < 4; ++t) {
            if (t < b) {
                unsigned key = __shfl(myk, j + t, 64);
                kk[t] = (int)(key >> 20);
                const f32x4* p = reinterpret_cast<const f32x4*>(
                    nodes + ((size_t)(key & 0xFFFFFu) << 9) + lane * 8);
                r[t][0] = p[0];
                r[t][1] = p[1];
            }
        }
        #pragma unroll
        for (int t = 0; t < 4; ++t) {
            if (t < b) {
                if (kk[t] != curk) {
                    if (curk >= 0) flush();
                    curk = kk[t];
                    f32x4 z = {0.f,0.f,0.f,0.f}; a0 = z; a1 = z;
                }
                a0 += r[t][0];
                a1 += r[t][1];
            }
        }
        j += 4;
    }
    if (curk >= 0) flush();
}

extern "C" void kernel_launch(void* const* d_in, const int* in_sizes, int n_in,
                              void* d_out, int out_size, void* d_ws, size_t ws_size,
                              hipStream_t stream) {
    const float* nodes      = (const float*)d_in[0];
    const int*   center_ind = (const int*)d_in[1];
    int K = in_sizes[1];                  // 1024
    int D = out_size / K;                 // 512 (DD)
    int N = in_sizes[0] / D;              // 100000

    char* ws = (char*)d_ws;
    _Float16* centf      = (_Float16*)ws;                          // K*DD*2 = 1 MB
    size_t    o          = (size_t)K * DD * 2;
    float*    cent_sq    = (float*)(ws + o);    o += (size_t)K * 4;
    unsigned* assignment = (unsigned*)(ws + o); o += (size_t)N * 4;
    unsigned* counts     = (unsigned*)(ws + o); o += (size_t)K * 4;
    unsigned* cursor     = (unsigned*)(ws + o); o += (size_t)K * 4;
    unsigned* firstk     = (unsigned*)(ws + o); o += (size_t)D * 4;
    unsigned* canon      = (unsigned*)(ws + o); o += (size_t)K * 4;
    unsigned* keys       = (unsigned*)(ws + o); o += (size_t)N * 4;
    float*    out        = (float*)d_out;

    hipMemsetAsync(counts, 0, (size_t)K * sizeof(unsigned), stream);
    hipMemsetAsync(firstk, 0xFF, (size_t)D * sizeof(unsigned), stream);
    hipMemsetAsync(out, 0, (size_t)out_size * sizeof(float), stream);

    canon_first<<<(K + 255) / 256, 256, 0, stream>>>(center_ind, firstk, K);
    canon_map<<<(K + 255) / 256, 256, 0, stream>>>(center_ind, firstk, canon, K);
    gather_centers<<<K, 64, 0, stream>>>(nodes, center_ind, centf, cent_sq, K);
    assign_mfma<<<(N + 63) / 64, 256, 0, stream>>>(nodes, centf, cent_sq, canon,
                                                   assignment, counts, N, K);
    scan_offsets<<<1, KK, 0, stream>>>(counts, cursor);
    scatter_idx<<<(N + 255) / 256, 256, 0, stream>>>(assignment, cursor, keys, N);
    aggregate3<<<(N + 4 * CHUNK - 1) / (4 * CHUNK), 256, 0, stream>>>(nodes, keys, out, N);
}